// Round 7
// baseline (67.863 us; speedup 1.0000x reference)
//
#include <hip/hip_runtime.h>

typedef unsigned short u16;
typedef unsigned int u32;
typedef __attribute__((ext_vector_type(8))) __bf16 bf16x8;
typedef __attribute__((ext_vector_type(4))) float f32x4;

#define S_LEN 169
#define SP 192

// ---------------- workspace layout (bytes)
#define W2T_WS 0                          // bf16 [256][192] = 98304
#define KE_WS  147456                     // f32 [256][176][16] = 2883584
#define KV_WS  (147456 + 2883584)
#define SG_WS  (147456 + 2 * 2883584)

// ---------------- S kernel LDS
#define SKE  0
#define SKV  11264
#define SG2  22528
#define SKVT 33792
#define SRB  39936
#define SSS  60416
#define SOW  61440
#define S_LDS 66560

// ---------------- kernel1: blocks 0..191 = w2t; blocks 192..959 = GEMM1+epilogue.
// G-block = (b, slab of 64 t-rows), 192 thr = 3 waves, wave wid owns matrix wid (k/v/r).
// NO LDS staging, NO main-loop barriers: A- and B-fragments load straight from global
// in MFMA layout (lane(q,hs): 8 consecutive f32 -> cvt -> bf16x8). One barrier total.
__global__ __launch_bounds__(192, 3) void k1_kernel(
    const float* __restrict__ x,
    const float* __restrict__ time_w,
    const float* __restrict__ time_alpha,
    const float* __restrict__ time_beta,
    const float* __restrict__ key_w,  const float* __restrict__ key_b,
    const float* __restrict__ value_w,const float* __restrict__ value_b,
    const float* __restrict__ recep_w,const float* __restrict__ recep_b,
    char* __restrict__ ws)
{
    __shared__ __align__(16) char smem[12288];
    const int tid = threadIdx.x;
    __bf16* w2t = (__bf16*)(ws + W2T_WS);
    int blk = blockIdx.x;

    if (blk < 192) {
        // ---- W path: w2t[t][s] = beta[s,t] * sum_{u<=t} tw[s,255+u-t]*alpha[s,u]
        const int s = blk;
        if (s >= S_LEN) {
            for (int t = tid; t < 256; t += 192) w2t[t * SP + s] = (__bf16)0.f;
            return;
        }
        float* tw = (float*)smem;            // [256]
        float* al = (float*)(smem + 1024);   // [256]
        for (int i = tid; i < 256; i += 192) {
            tw[i] = time_w[s * 256 + i];
            al[i] = time_alpha[s * 256 + i];
        }
        __syncthreads();
        for (int t = tid; t < 256; t += 192) {
            float acc = 0.f;
            for (int u = 0; u <= t; ++u)
                acc = fmaf(tw[255 + u - t], al[u], acc);
            w2t[t * SP + s] = (__bf16)(time_beta[s * 256 + t] * acc);
        }
        return;
    }

    // ---- G path
    blk -= 192;
    const int b    = blk / 3;
    const int slab = blk - b * 3;
    const int t0   = slab * 64;
    const int lane = tid & 63;
    const int wid  = tid >> 6;       // 0..2 -> key/value/recep
    const int q    = lane >> 4;
    const int hs   = lane & 15;
    const float* xb = x + (size_t)b * (S_LEN * 512);

    // B-fragments straight from f32 weights (L2-hot): lane(q,hs) = W[hs][ks*32+q*8 ..+8]
    const float* wmat = (wid == 0) ? key_w : (wid == 1) ? value_w : recep_w;
    bf16x8 bfrag[16];
    #pragma unroll
    for (int ks = 0; ks < 16; ++ks) {
        const float* src = wmat + hs * 512 + ks * 32 + q * 8;
        float4 w0 = *(const float4*)src;
        float4 w1 = *(const float4*)(src + 4);
        bf16x8 p;
        p[0]=(__bf16)w0.x; p[1]=(__bf16)w0.y; p[2]=(__bf16)w0.z; p[3]=(__bf16)w0.w;
        p[4]=(__bf16)w1.x; p[5]=(__bf16)w1.y; p[6]=(__bf16)w1.z; p[7]=(__bf16)w1.w;
        bfrag[ks] = p;
    }

    // A-fragments direct from x; ks<8 uses row-1 (channel shift), ks>=8 row.
    f32x4 acc[4];
    #pragma unroll
    for (int mt = 0; mt < 4; ++mt) acc[mt] = (f32x4){0.f, 0.f, 0.f, 0.f};

    #pragma unroll
    for (int mt = 0; mt < 4; ++mt) {
        const int rA  = t0 + mt * 16 + hs;            // output row for this lane
        const int rS  = rA - 1;
        const bool neg = (rS < 0);
        const int rSc = neg ? 0 : (rS > S_LEN - 1 ? S_LEN - 1 : rS);
        const int rNc = (rA > S_LEN - 1) ? S_LEN - 1 : rA;
        const float* baseS = xb + (size_t)rSc * 512;
        const float* baseN = xb + (size_t)rNc * 512;
        #pragma unroll
        for (int ks = 0; ks < 16; ++ks) {
            const float* s = ((ks < 8) ? baseS : baseN) + ks * 32 + q * 8;
            float4 f0 = *(const float4*)s;
            float4 f1 = *(const float4*)(s + 4);
            if (ks < 8 && neg) { f0 = (float4){0.f,0.f,0.f,0.f}; f1 = (float4){0.f,0.f,0.f,0.f}; }
            bf16x8 a;
            a[0]=(__bf16)f0.x; a[1]=(__bf16)f0.y; a[2]=(__bf16)f0.z; a[3]=(__bf16)f0.w;
            a[4]=(__bf16)f1.x; a[5]=(__bf16)f1.y; a[6]=(__bf16)f1.z; a[7]=(__bf16)f1.w;
            acc[mt] = __builtin_amdgcn_mfma_f32_16x16x32_bf16(a, bfrag[ks], acc[mt], 0, 0, 0);
        }
    }

    // epilogue: raw (+bias) -> LDS [3][64][16] f32; one barrier; combine -> ws
    float* raw = (float*)smem;
    {
        const float* bv = (wid == 0) ? key_b : (wid == 1) ? value_b : recep_b;
        const float bias = bv[hs];
        #pragma unroll
        for (int mt = 0; mt < 4; ++mt) {
            #pragma unroll
            for (int rg = 0; rg < 4; ++rg) {
                int tl = mt * 16 + q * 4 + rg;
                raw[wid * 1024 + tl * 16 + hs] = acc[mt][rg] + bias;
            }
        }
    }
    __syncthreads();
    float* keg = (float*)(ws + KE_WS);
    float* kvg = (float*)(ws + KV_WS);
    float* sgg = (float*)(ws + SG_WS);
    for (int i = tid; i < 1024; i += 192) {
        int tl = i >> 4, h = i & 15;
        int t  = t0 + tl;
        if (t < S_LEN) {
            float kk = fminf(fmaxf(raw[i], -60.f), 30.f);
            float ke = __expf(kk);
            size_t o = ((size_t)b * 176 + t) * 16 + h;
            keg[o] = ke;
            kvg[o] = ke * raw[1024 + i];
            sgg[o] = 1.f / (1.f + __expf(-raw[2048 + i]));
        }
    }
}

// ---------------- kernel S: scan + wkv + out-proj. 256 blocks (one per b)
__global__ __launch_bounds__(256) void scan_kernel(
    const char* __restrict__ wsr,
    const float* __restrict__ out_w, const float* __restrict__ out_b,
    const float* __restrict__ gamma,
    float* __restrict__ out)
{
    __shared__ __align__(16) char smem[S_LDS];
    const int tid  = threadIdx.x;
    const int lane = tid & 63;
    const int wid  = tid >> 6;
    const int q    = lane >> 4;
    const int hs   = lane & 15;
    const int b    = blockIdx.x;
    const __bf16* w2t = (const __bf16*)(wsr + W2T_WS);
    const float4* keb = (const float4*)(wsr + KE_WS + (size_t)b * 11264);
    const float4* kvb = (const float4*)(wsr + KV_WS + (size_t)b * 11264);
    const float4* sgb = (const float4*)(wsr + SG_WS + (size_t)b * 11264);

    #pragma unroll
    for (int it = 0; it < 3; ++it) {
        int i = tid + (it << 8);
        if (i < 676) {
            ((float4*)(smem + SKE))[i] = keb[i];
            ((float4*)(smem + SKV))[i] = kvb[i];
            ((float4*)(smem + SG2))[i] = sgb[i];
        }
    }
    for (int i = tid; i < 2560; i += 256) {
        int o = i / 40, c = i - o * 40;
        ((__bf16*)(smem + SOW))[i] = (c < 16) ? (__bf16)out_w[o * 16 + c] : (__bf16)0.f;
    }
    for (int i = tid; i < 4096; i += 256) {
        int row = i >> 4, c = 16 + (i & 15);
        ((__bf16*)(smem + SRB))[row * 40 + c] = (__bf16)0.f;
    }
    for (int i = tid; i < 368; i += 256) {
        int h2 = i & 15; int t = S_LEN + (i >> 4);
        u32 off = ((u32)(h2 * 384 + t * 2)) ^ (((u32)(h2 & 7)) << 4);
        *(__bf16*)(smem + SKVT + off) = (__bf16)0.f;
    }
    __syncthreads();

    float* KE = (float*)(smem + SKE);
    float* KV = (float*)(smem + SKV);
    float* GG = (float*)(smem + SG2);
    float* SEG = (float*)(smem + SSS);
    const int h  = tid & 15;
    const int sg = tid >> 4;
    const int ts = sg * 11;
    const int te = (ts + 11 < S_LEN) ? ts + 11 : S_LEN;
    {
        float ssum = 0.f;
        for (int t = ts; t < te; ++t) ssum += KE[t * 16 + h];
        SEG[sg * 16 + h] = ssum;
    }
    __syncthreads();
    {
        float run = 0.f;
        for (int s2 = 0; s2 < sg; ++s2) run += SEG[s2 * 16 + h];
        for (int t = ts; t < te; ++t) {
            run += KE[t * 16 + h];
            u32 off = ((u32)(h * 384 + t * 2)) ^ (((u32)(h & 7)) << 4);
            *(__bf16*)(smem + SKVT + off) = (__bf16)KV[t * 16 + h];
            GG[t * 16 + h] = GG[t * 16 + h] / run;
        }
    }
    __syncthreads();

    f32x4 wa[4];
    #pragma unroll
    for (int mi = 0; mi < 4; ++mi) wa[mi] = (f32x4){0.f,0.f,0.f,0.f};
    #pragma unroll
    for (int s0 = 0; s0 < SP; s0 += 32) {
        int scol = s0 + (q << 3);
        u32 boff = ((u32)(hs * 384 + scol * 2)) ^ (((u32)(hs & 7)) << 4);
        bf16x8 bfr = *(const bf16x8*)(smem + SKVT + boff);
        #pragma unroll
        for (int mi = 0; mi < 4; ++mi) {
            int row = (wid + (mi << 2)) * 16 + hs;
            bf16x8 afr = *(const bf16x8*)(w2t + row * SP + scol);
            wa[mi] = __builtin_amdgcn_mfma_f32_16x16x32_bf16(afr, bfr, wa[mi], 0,0,0);
        }
    }
    #pragma unroll
    for (int mi = 0; mi < 4; ++mi) {
        int tb = (wid + (mi << 2)) * 16 + (q << 2);
        #pragma unroll
        for (int rg = 0; rg < 4; ++rg) {
            int t = tb + rg;
            float fac = (t < S_LEN) ? GG[t * 16 + hs] : 0.5f;
            ((__bf16*)(smem + SRB))[t * 40 + hs] = (__bf16)(wa[mi][rg] * fac);
        }
    }
    __syncthreads();

    float obv[4];
    #pragma unroll
    for (int nt = 0; nt < 4; ++nt) obv[nt] = out_b[nt * 16 + hs];
    #pragma unroll
    for (int mi = 0; mi < 4; ++mi) {
        int mt = wid + (mi << 2);
        int arow = mt * 16 + hs;
        bf16x8 afr = *(const bf16x8*)(smem + SRB + (u32)(arow * 80 + (q << 4)));
        float gm[4];
        #pragma unroll
        for (int rg = 0; rg < 4; ++rg) gm[rg] = gamma[mt * 16 + (q << 2) + rg];
        #pragma unroll
        for (int nt = 0; nt < 4; ++nt) {
            int orow = nt * 16 + hs;
            bf16x8 bfr = *(const bf16x8*)(smem + SOW + (u32)(orow * 80 + (q << 4)));
            f32x4 zc = (f32x4){0.f,0.f,0.f,0.f};
            f32x4 d = __builtin_amdgcn_mfma_f32_16x16x32_bf16(afr, bfr, zc, 0,0,0);
            #pragma unroll
            for (int rg = 0; rg < 4; ++rg) {
                int t = mt * 16 + (q << 2) + rg;
                out[(size_t)b * 16384 + (size_t)t * 64 + nt * 16 + hs] = (d[rg] + obv[nt]) * gm[rg];
            }
        }
    }
}

extern "C" void kernel_launch(void* const* d_in, const int* in_sizes, int n_in,
                              void* d_out, int out_size, void* d_ws, size_t ws_size,
                              hipStream_t stream) {
    const float* x          = (const float*)d_in[0];
    const float* time_w     = (const float*)d_in[1];
    const float* time_alpha = (const float*)d_in[2];
    const float* time_beta  = (const float*)d_in[3];
    const float* time_gamma = (const float*)d_in[4];
    const float* key_w      = (const float*)d_in[5];
    const float* key_b      = (const float*)d_in[6];
    const float* value_w    = (const float*)d_in[7];
    const float* value_b    = (const float*)d_in[8];
    const float* recep_w    = (const float*)d_in[9];
    const float* recep_b    = (const float*)d_in[10];
    const float* out_w      = (const float*)d_in[11];
    const float* out_b      = (const float*)d_in[12];
    char* ws = (char*)d_ws;

    k1_kernel<<<960, 192, 0, stream>>>(x, time_w, time_alpha, time_beta,
                                       key_w, key_b, value_w, value_b,
                                       recep_w, recep_b, ws);
    scan_kernel<<<256, 256, 0, stream>>>(ws, out_w, out_b, time_gamma, (float*)d_out);
}